// Round 16
// baseline (43.988 us; speedup 1.0000x reference)
//
#include <hip/hip_runtime.h>
#include <hip/hip_bf16.h>
#include <hip/hip_fp16.h>
#include <math.h>

#define Bq 2048
#define Nn 1024
#define Dd 128
#define Cc 10
#define MM 16                  // batch rows per block (MFMA M)
#define NBLK (Bq / MM)         // 128 dist-blocks
#define NTH 1024               // 16 waves
#define NC (Nn * Cc)           // 10240
#define PART_HALFS (NBLK * NC) // 1.31M halfs = 2.6 MB

// d_out layout (floats): [0, B*C) = labels[bmu]; [B*C, B*C+N*C) = activities; last C = counts
#define ACT_OFF (Bq * Cc)
#define CNT_OFF (Bq * Cc + Nn * Cc)

// ws layout (bytes): fp16 partials; cls ints; 256B-aligned nbh ([16][1024] x 16B); ns2
#define WS_CLS_BYTE  (PART_HALFS * 2)
#define WS_NBH_BYTE  (((WS_CLS_BYTE + Bq * 4) + 255) & ~255)
#define WS_NS2_BYTE  (WS_NBH_BYTE + 16 * Nn * 16)
#define WS_NEED_BYTES (WS_NS2_BYTE + Nn * 4)

typedef __attribute__((ext_vector_type(8))) short short8;   // 8 bf16 (4 VGPRs)
typedef __attribute__((ext_vector_type(4))) float f32x4;    // MFMA C/D

__device__ __forceinline__ ushort f2bf(float v, float* back) {
    __hip_bfloat16 h = __float2bfloat16(v);
    *back = __bfloat162float(h);
    return *(const ushort*)&h;
}

// ---------------- prep: neurons -> bf16 B-table nbh[kb][n] + ns2 of the ROUNDED values ----------------
__global__ __launch_bounds__(256) void som_prep(
    const float* __restrict__ neurons,
    short8* __restrict__ nbh,   // [16][Nn]
    float* __restrict__ ns2)    // [Nn]
{
    __shared__ ushort hsh[8][128];
    const int t     = threadIdx.x;
    const int base8 = blockIdx.x * 8;    // 8 neuron rows per block

    const int r = t >> 5;
    const int c = (t * 4) & 127;
    float4 v = *(const float4*)&neurons[(long)(base8 + r) * Dd + c];
    float back, s;
    ushort h0 = f2bf(v.x, &back); s  = back * back;
    ushort h1 = f2bf(v.y, &back); s += back * back;
    ushort h2 = f2bf(v.z, &back); s += back * back;
    ushort h3 = f2bf(v.w, &back); s += back * back;
    hsh[r][c + 0] = h0;
    hsh[r][c + 1] = h1;
    hsh[r][c + 2] = h2;
    hsh[r][c + 3] = h3;

    #pragma unroll
    for (int off = 16; off; off >>= 1) s += __shfl_xor(s, off);
    if ((t & 31) == 0) ns2[base8 + r] = s;
    __syncthreads();

    if (t < 128) {
        int r2 = t >> 4, kb = t & 15;
        nbh[kb * Nn + base8 + r2] = *(const short8*)&hsh[r2][kb * 8];
    }
}

// ---------------- main kernel: 2-pass split-x MFMA + LDS-atomic partials epilogue ----------------
__global__ __launch_bounds__(NTH) void som_dist(
    const float* __restrict__ x,
    const float* __restrict__ y,
    const short8* __restrict__ nbh,   // [16][Nn]
    const float* __restrict__ ns2,
    const float* __restrict__ labels,
    const float* __restrict__ sigma,
    float* __restrict__ out,
    __half* __restrict__ ws_p,    // [NBLK][Cc][Nn] fp16
    int*   __restrict__ ws_cls)   // [Bq]
{
    __shared__ ushort xsh[MM * 128];   // swizzled bf16-hi of x rows (4 KB)
    __shared__ ushort xsl[MM * 128];   // bf16-lo (4 KB)
    __shared__ float  pls[Cc][Nn];     // per-class partial scatter (40 KB); wave w owns cols [w*64, w*64+64)
    __shared__ float  xs2s[MM];
    __shared__ float  candv[16][MM];
    __shared__ int    candi[16][MM];
    __shared__ float  bmu_d[MM];
    __shared__ int    bmu_i[MM];
    __shared__ int    clss[MM];

    const int t    = threadIdx.x;
    const int b0   = blockIdx.x * MM;
    const int w    = t >> 6;          // wave 0..15: owns cols w*64 .. +63
    const int lane = t & 63;
    const int g    = lane >> 4;       // 16-lane group 0..3
    const int c16  = lane & 15;

    // ---- stage x rows as split-bf16 in LDS (XOR-swizzled 16B chunks) ----
    #pragma unroll
    for (int ii = 0; ii < 2; ++ii) {
        int i   = t + ii * 1024;      // 0..2047
        int row = i >> 7;
        int k   = i & 127;
        float v = x[(b0 + row) * Dd + k];
        float back; ushort h = f2bf(v, &back);
        float lo = v - back;
        float b2; ushort l = f2bf(lo, &b2);
        int kb  = k >> 3, j = k & 7;
        int idx = row * 128 + ((kb ^ (row & 7)) << 3) + j;
        xsh[idx] = h;
        xsl[idx] = l;
    }

    // init this wave's pls region (10 classes x 64 cols)
    #pragma unroll
    for (int c = 0; c < Cc; ++c) pls[c][w * 64 + lane] = 0.f;

    // xs2[row w] (exact fp32)
    {
        float v0 = x[(b0 + w) * Dd + lane];
        float v1 = x[(b0 + w) * Dd + lane + 64];
        float s  = fmaf(v0, v0, v1 * v1);
        #pragma unroll
        for (int off = 32; off; off >>= 1) s += __shfl_xor(s, off);
        if (lane == 0) xs2s[w] = s;
    }
    __syncthreads();

    // ---- MFMA: dot[b][n] = (xh + xl) . nb  (2-pass split-x, fp32 accum) ----
    float dvv[4][4];
    float mval[4]; int midx[4];
    #pragma unroll
    for (int r = 0; r < 4; ++r) { mval[r] = 3.4e38f; midx[r] = 0; }

    const int rowa  = c16;
    const int abase = rowa * 128;
    const int axor  = (rowa & 7);

    #pragma unroll
    for (int ti = 0; ti < 4; ++ti) {
        const int n0 = w * 64 + ti * 16;
        f32x4 acc = {0.f, 0.f, 0.f, 0.f};
        #pragma unroll
        for (int ks = 0; ks < 4; ++ks) {
            const int kb = ks * 4 + g;
            const int ai = abase + ((kb ^ axor) << 3);
            short8 ah = *(const short8*)&xsh[ai];
            short8 al = *(const short8*)&xsl[ai];
            short8 bh = nbh[kb * Nn + n0 + c16];
            acc = __builtin_amdgcn_mfma_f32_16x16x32_bf16(ah, bh, acc, 0, 0, 0);
            acc = __builtin_amdgcn_mfma_f32_16x16x32_bf16(al, bh, acc, 0, 0, 0);
        }
        const float ns2v = ns2[n0 + c16];
        #pragma unroll
        for (int r = 0; r < 4; ++r) {
            float dv = fmaf(-2.f, acc[r], ns2v);   // shifted d2 (argmin-safe)
            dvv[ti][r] = dv;
            if (dv < mval[r]) { mval[r] = dv; midx[r] = n0 + c16; }  // n ascending: strict < keeps first
        }
    }

    // ---- argmin: 16-lane group reduce (row = g*4+r), then 16-wave combine ----
    #pragma unroll
    for (int r = 0; r < 4; ++r) {
        float bv = mval[r]; int bi = midx[r];
        #pragma unroll
        for (int off = 8; off; off >>= 1) {
            float ov = __shfl_xor(bv, off);
            int   oi = __shfl_xor(bi, off);
            if (ov < bv || (ov == bv && oi < bi)) { bv = ov; bi = oi; }
        }
        if (c16 == 0) { candv[w][g * 4 + r] = bv; candi[w][g * 4 + r] = bi; }
    }
    __syncthreads();

    if (t < MM) {
        float best = candv[0][t]; int bidx = candi[0][t];
        #pragma unroll
        for (int w2 = 1; w2 < 16; ++w2) {
            float v = candv[w2][t]; int i2 = candi[w2][t];
            if (v < best || (v == best && i2 < bidx)) { best = v; bidx = i2; }
        }
        bmu_i[t] = bidx;
        float d2 = xs2s[t] + best;
        bmu_d[t] = sqrtf(d2 > 0.f ? d2 : 0.f);

        // cls = argmax_c y[b][c] (strict > keeps first, matching jnp.argmax)
        const float* yr = y + (long)(b0 + t) * Cc;
        float bvv = yr[0]; int bc = 0;
        #pragma unroll
        for (int c = 1; c < Cc; ++c) { float v = yr[c]; if (v > bvv) { bvv = v; bc = c; } }
        clss[t] = bc;
        ws_cls[b0 + t] = bc;
    }
    __syncthreads();

    // out rows: labels[bmu[b]]
    if (t < MM * Cc) {
        int b = t / Cc, c = t % Cc;
        out[(b0 + b) * Cc + c] = labels[bmu_i[b] * Cc + c];
    }

    // ---- partials: LDS float-atomic scatter per (class, col), then coalesced fp16 write ----
    const float inv_sig = 1.f / sigma[0];

    #pragma unroll
    for (int ti = 0; ti < 4; ++ti) {
        const int col = w * 64 + ti * 16 + c16;
        #pragma unroll
        for (int r = 0; r < 4; ++r) {
            const int row = g * 4 + r;
            float d2 = xs2s[row] + dvv[ti][r];
            float d  = sqrtf(d2 > 0.f ? d2 : 0.f);
            float gn = expf((bmu_d[row] - d) * inv_sig);
            atomicAdd(&pls[clss[row]][col], gn);
        }
    }
    __syncthreads();

    // write-out: lane covers col w*64 + lane, all 10 classes (coalesced stores)
    __half* pb = ws_p + (long)blockIdx.x * NC;
    #pragma unroll
    for (int c = 0; c < Cc; ++c) {
        pb[c * Nn + w * 64 + lane] = __float2half(pls[c][w * 64 + lane]);
    }
}

// ---------------- final reduction: 160 j-blocks x 4 k-chunks (32 each) + histogram ----------------
__global__ __launch_bounds__(256) void som_fin(
    const float* __restrict__ act_in,
    const int*   __restrict__ cnt_in,
    const __half* __restrict__ ws_p,
    const int*   __restrict__ ws_cls,
    float* __restrict__ out)
{
    if (blockIdx.x < 160) {
        const int t  = threadIdx.x;
        const int kc = t & 3;                       // k-chunk 0..3 (32 partial-blocks each)
        const int j  = blockIdx.x * 64 + (t >> 2);  // j = c*Nn + n
        const int c  = j >> 10;
        const int n  = j & (Nn - 1);
        const __half* p = ws_p + (long)(kc * 32) * NC + j;
        float s = 0.f;
        #pragma unroll 8
        for (int i = 0; i < 32; ++i) s += __half2float(p[(long)i * NC]);
        s += __shfl_down(s, 2);
        s += __shfl_down(s, 1);
        if (kc == 0) out[ACT_OFF + n * Cc + c] = act_in[n * Cc + c] + s;
    } else {
        __shared__ int hist[Cc];
        if (threadIdx.x < Cc) hist[threadIdx.x] = 0;
        __syncthreads();
        for (int b = threadIdx.x; b < Bq; b += 256) atomicAdd(&hist[ws_cls[b]], 1);
        __syncthreads();
        if (threadIdx.x < Cc)
            out[CNT_OFF + threadIdx.x] = (float)(cnt_in[threadIdx.x] + hist[threadIdx.x]);
    }
}

// ---------------- fallback path (atomic-based, known-good) ----------------
__global__ void som_init(const float* __restrict__ act_in,
                         const int* __restrict__ cnt_in,
                         float* __restrict__ out) {
    int i = blockIdx.x * blockDim.x + threadIdx.x;
    if (i < Nn * Cc) out[ACT_OFF + i] = act_in[i];
    if (i < Cc) out[CNT_OFF + i] = (float)cnt_in[i];
}

__global__ __launch_bounds__(512) void som_main(
    const float* __restrict__ x,
    const float* __restrict__ y,
    const float* __restrict__ neurons,
    const float* __restrict__ labels,
    const float* __restrict__ sigma,
    float* __restrict__ out)
{
    __shared__ float xs[8][Dd];
    __shared__ float d2s[8][Nn];
    __shared__ float bmu_d[8];
    __shared__ int   bmu_i[8];
    __shared__ int   clss[8];

    const int t  = threadIdx.x;
    const int b0 = blockIdx.x * 8;

    for (int i = t; i < 8 * Dd; i += 512)
        xs[i >> 7][i & (Dd - 1)] = x[b0 * Dd + i];
    __syncthreads();

    float acc0[8], acc1[8];
    #pragma unroll
    for (int b = 0; b < 8; ++b) { acc0[b] = 0.f; acc1[b] = 0.f; }

    const float4* nr0 = (const float4*)(neurons + t * Dd);
    const float4* nr1 = (const float4*)(neurons + (t + 512) * Dd);

    #pragma unroll 2
    for (int dc = 0; dc < Dd / 4; ++dc) {
        float4 nv0 = nr0[dc];
        float4 nv1 = nr1[dc];
        #pragma unroll
        for (int b = 0; b < 8; ++b) {
            float4 xv = *(const float4*)&xs[b][dc * 4];
            float d;
            d = xv.x - nv0.x; acc0[b] = fmaf(d, d, acc0[b]);
            d = xv.y - nv0.y; acc0[b] = fmaf(d, d, acc0[b]);
            d = xv.z - nv0.z; acc0[b] = fmaf(d, d, acc0[b]);
            d = xv.w - nv0.w; acc0[b] = fmaf(d, d, acc0[b]);
            d = xv.x - nv1.x; acc1[b] = fmaf(d, d, acc1[b]);
            d = xv.y - nv1.y; acc1[b] = fmaf(d, d, acc1[b]);
            d = xv.z - nv1.z; acc1[b] = fmaf(d, d, acc1[b]);
            d = xv.w - nv1.w; acc1[b] = fmaf(d, d, acc1[b]);
        }
    }

    #pragma unroll
    for (int b = 0; b < 8; ++b) {
        d2s[b][t]       = acc0[b];
        d2s[b][t + 512] = acc1[b];
    }
    __syncthreads();

    {
        const int wv = t >> 6, lane = t & 63;
        float best = 3.4e38f; int bidx = 0;
        #pragma unroll
        for (int i = 0; i < Nn / 64; ++i) {
            int idx = lane + i * 64;
            float v = d2s[wv][idx];
            if (v < best) { best = v; bidx = idx; }
        }
        #pragma unroll
        for (int off = 32; off; off >>= 1) {
            float ov = __shfl_down(best, off);
            int   oi = __shfl_down(bidx, off);
            if (ov < best || (ov == best && oi < bidx)) { best = ov; bidx = oi; }
        }
        if (lane == 0) { bmu_i[wv] = bidx; bmu_d[wv] = sqrtf(best); }
    }

    if (t < 8) {
        const float* yr = y + (long)(b0 + t) * Cc;
        float bv = yr[0]; int bc = 0;
        #pragma unroll
        for (int c = 1; c < Cc; ++c) { float v = yr[c]; if (v > bv) { bv = v; bc = c; } }
        clss[t] = bc;
        atomicAdd(out + CNT_OFF + bc, 1.0f);
    }
    __syncthreads();

    for (int i = t; i < 8 * Cc; i += 512) {
        int b = i / Cc, c = i % Cc;
        out[(long)(b0 + b) * Cc + c] = labels[(long)bmu_i[b] * Cc + c];
    }

    const float sig = sigma[0];
    #pragma unroll
    for (int b = 0; b < 8; ++b) {
        float gb = expf(-bmu_d[b] / sig);
        int   cl = clss[b];
        float g0 = expf(-sqrtf(acc0[b]) / sig);
        float g1 = expf(-sqrtf(acc1[b]) / sig);
        float gn0 = (gb == 0.f) ? 0.f : g0 / gb;
        float gn1 = (gb == 0.f) ? 0.f : g1 / gb;
        atomicAdd(out + ACT_OFF + t * Cc + cl, gn0);
        atomicAdd(out + ACT_OFF + (t + 512) * Cc + cl, gn1);
    }
}

extern "C" void kernel_launch(void* const* d_in, const int* in_sizes, int n_in,
                              void* d_out, int out_size, void* d_ws, size_t ws_size,
                              hipStream_t stream) {
    const float* x       = (const float*)d_in[0];
    const float* y       = (const float*)d_in[1];
    const float* neurons = (const float*)d_in[2];
    const float* labels  = (const float*)d_in[3];
    const float* act     = (const float*)d_in[4];
    const int*   cnt     = (const int*)d_in[5];
    const float* sigma   = (const float*)d_in[6];
    float* out = (float*)d_out;

    if (ws_size >= (size_t)WS_NEED_BYTES) {
        char*   wsb    = (char*)d_ws;
        __half* ws_p   = (__half*)wsb;
        int*    ws_cls = (int*)(wsb + WS_CLS_BYTE);
        short8* ws_nbh = (short8*)(wsb + WS_NBH_BYTE);
        float*  ws_ns2 = (float*)(wsb + WS_NS2_BYTE);
        som_prep<<<128, 256, 0, stream>>>(neurons, ws_nbh, ws_ns2);
        som_dist<<<NBLK, NTH, 0, stream>>>(x, y, ws_nbh, ws_ns2, labels, sigma, out, ws_p, ws_cls);
        som_fin<<<161, 256, 0, stream>>>(act, cnt, ws_p, ws_cls, out);
    } else {
        som_init<<<(Nn * Cc + 255) / 256, 256, 0, stream>>>(act, cnt, out);
        som_main<<<Bq / 8, 512, 0, stream>>>(x, y, neurons, labels, sigma, out);
    }
}

// Round 17
// 31.849 us; speedup vs baseline: 1.3812x; 1.3812x over previous
//
#include <hip/hip_runtime.h>
#include <hip/hip_bf16.h>
#include <hip/hip_fp16.h>
#include <math.h>

#define Bq 2048
#define Nn 1024
#define Dd 128
#define Cc 10
#define MM 16                  // batch rows per block (MFMA M)
#define NBLK (Bq / MM)         // 128 dist-blocks
#define NTH 1024               // 16 waves
#define NC (Nn * Cc)           // 10240
#define PART_HALFS (NBLK * NC) // 1.31M halfs = 2.6 MB

// d_out layout (floats): [0, B*C) = labels[bmu]; [B*C, B*C+N*C) = activities; last C = counts
#define ACT_OFF (Bq * Cc)
#define CNT_OFF (Bq * Cc + Nn * Cc)

// ws layout (bytes): fp16 partials; cls ints; 256B-aligned nbh ([16][1024] x 16B); ns2
#define WS_CLS_BYTE  (PART_HALFS * 2)
#define WS_NBH_BYTE  (((WS_CLS_BYTE + Bq * 4) + 255) & ~255)
#define WS_NS2_BYTE  (WS_NBH_BYTE + 16 * Nn * 16)
#define WS_NEED_BYTES (WS_NS2_BYTE + Nn * 4)

typedef __attribute__((ext_vector_type(8))) short short8;   // 8 bf16 (4 VGPRs)
typedef __attribute__((ext_vector_type(4))) float f32x4;    // MFMA C/D

__device__ __forceinline__ ushort f2bf(float v, float* back) {
    __hip_bfloat16 h = __float2bfloat16(v);
    *back = __bfloat162float(h);
    return *(const ushort*)&h;
}

// ---------------- prep: neurons -> bf16 B-table nbh[kb][n] + ns2 of the ROUNDED values ----------------
__global__ __launch_bounds__(256) void som_prep(
    const float* __restrict__ neurons,
    short8* __restrict__ nbh,   // [16][Nn]
    float* __restrict__ ns2)    // [Nn]
{
    __shared__ ushort hsh[8][128];
    const int t     = threadIdx.x;
    const int base8 = blockIdx.x * 8;    // 8 neuron rows per block

    const int r = t >> 5;
    const int c = (t * 4) & 127;
    float4 v = *(const float4*)&neurons[(long)(base8 + r) * Dd + c];
    float back, s;
    ushort h0 = f2bf(v.x, &back); s  = back * back;
    ushort h1 = f2bf(v.y, &back); s += back * back;
    ushort h2 = f2bf(v.z, &back); s += back * back;
    ushort h3 = f2bf(v.w, &back); s += back * back;
    hsh[r][c + 0] = h0;
    hsh[r][c + 1] = h1;
    hsh[r][c + 2] = h2;
    hsh[r][c + 3] = h3;

    #pragma unroll
    for (int off = 16; off; off >>= 1) s += __shfl_xor(s, off);
    if ((t & 31) == 0) ns2[base8 + r] = s;
    __syncthreads();

    if (t < 128) {
        int r2 = t >> 4, kb = t & 15;
        nbh[kb * Nn + base8 + r2] = *(const short8*)&hsh[r2][kb * 8];
    }
}

// ---------------- main kernel: single-pass bf16 MFMA (x rounded too) ----------------
// Metric: |bf16(x) - bf16(n)|^2, fully consistent (dot exact in fp32 accum,
// xs2 = sum(bf16(x)^2), ns2 = sum(bf16(n)^2)).
__global__ __launch_bounds__(NTH) void som_dist(
    const float* __restrict__ x,
    const float* __restrict__ y,
    const short8* __restrict__ nbh,   // [16][Nn]
    const float* __restrict__ ns2,
    const float* __restrict__ labels,
    const float* __restrict__ sigma,
    float* __restrict__ out,
    __half* __restrict__ ws_p,    // [NBLK][Cc][Nn] fp16
    int*   __restrict__ ws_cls)   // [Bq]
{
    __shared__ ushort xsh[MM * 128];   // swizzled bf16 of x rows (4 KB)
    __shared__ float  xs2s[MM];
    __shared__ float  candv[16][MM];
    __shared__ int    candi[16][MM];
    __shared__ float  bmu_d[MM];
    __shared__ int    bmu_i[MM];
    __shared__ int    clss[MM];

    const int t    = threadIdx.x;
    const int b0   = blockIdx.x * MM;
    const int w    = t >> 6;          // wave 0..15: owns cols w*64 .. +63
    const int lane = t & 63;
    const int g    = lane >> 4;       // 16-lane group 0..3
    const int c16  = lane & 15;

    // ---- stage x rows as bf16 in LDS (XOR-swizzled 16B chunks) ----
    #pragma unroll
    for (int ii = 0; ii < 2; ++ii) {
        int i   = t + ii * 1024;      // 0..2047
        int row = i >> 7;
        int k   = i & 127;
        float v = x[(b0 + row) * Dd + k];
        float back; ushort h = f2bf(v, &back);
        int kb  = k >> 3, j = k & 7;
        int idx = row * 128 + ((kb ^ (row & 7)) << 3) + j;
        xsh[idx] = h;
    }

    // xs2[row w] of the ROUNDED x (consistent metric)
    {
        float v0 = x[(b0 + w) * Dd + lane];
        float v1 = x[(b0 + w) * Dd + lane + 64];
        float r0, r1;
        f2bf(v0, &r0);
        f2bf(v1, &r1);
        float s = fmaf(r0, r0, r1 * r1);
        #pragma unroll
        for (int off = 32; off; off >>= 1) s += __shfl_xor(s, off);
        if (lane == 0) xs2s[w] = s;
    }
    __syncthreads();

    // ---- MFMA: dot[b][n] = bf16(x) . bf16(n)  (single pass, fp32 accum) ----
    float dvv[4][4];
    float mval[4]; int midx[4];
    #pragma unroll
    for (int r = 0; r < 4; ++r) { mval[r] = 3.4e38f; midx[r] = 0; }

    const int rowa  = c16;
    const int abase = rowa * 128;
    const int axor  = (rowa & 7);

    #pragma unroll
    for (int ti = 0; ti < 4; ++ti) {
        const int n0 = w * 64 + ti * 16;
        f32x4 acc = {0.f, 0.f, 0.f, 0.f};
        #pragma unroll
        for (int ks = 0; ks < 4; ++ks) {
            const int kb = ks * 4 + g;
            const int ai = abase + ((kb ^ axor) << 3);
            short8 ah = *(const short8*)&xsh[ai];
            short8 bh = nbh[kb * Nn + n0 + c16];
            acc = __builtin_amdgcn_mfma_f32_16x16x32_bf16(ah, bh, acc, 0, 0, 0);
        }
        const float ns2v = ns2[n0 + c16];
        #pragma unroll
        for (int r = 0; r < 4; ++r) {
            float dv = fmaf(-2.f, acc[r], ns2v);   // shifted d2 (argmin-safe)
            dvv[ti][r] = dv;
            if (dv < mval[r]) { mval[r] = dv; midx[r] = n0 + c16; }  // n ascending: strict < keeps first
        }
    }

    // ---- argmin: 16-lane group reduce (row = g*4+r), then 16-wave combine ----
    #pragma unroll
    for (int r = 0; r < 4; ++r) {
        float bv = mval[r]; int bi = midx[r];
        #pragma unroll
        for (int off = 8; off; off >>= 1) {
            float ov = __shfl_xor(bv, off);
            int   oi = __shfl_xor(bi, off);
            if (ov < bv || (ov == bv && oi < bi)) { bv = ov; bi = oi; }
        }
        if (c16 == 0) { candv[w][g * 4 + r] = bv; candi[w][g * 4 + r] = bi; }
    }
    __syncthreads();

    if (t < MM) {
        float best = candv[0][t]; int bidx = candi[0][t];
        #pragma unroll
        for (int w2 = 1; w2 < 16; ++w2) {
            float v = candv[w2][t]; int i2 = candi[w2][t];
            if (v < best || (v == best && i2 < bidx)) { best = v; bidx = i2; }
        }
        bmu_i[t] = bidx;
        float d2 = xs2s[t] + best;
        bmu_d[t] = sqrtf(d2 > 0.f ? d2 : 0.f);

        // cls = argmax_c y[b][c] (strict > keeps first, matching jnp.argmax)
        const float* yr = y + (long)(b0 + t) * Cc;
        float bvv = yr[0]; int bc = 0;
        #pragma unroll
        for (int c = 1; c < Cc; ++c) { float v = yr[c]; if (v > bvv) { bvv = v; bc = c; } }
        clss[t] = bc;
        ws_cls[b0 + t] = bc;
    }
    __syncthreads();

    // out rows: labels[bmu[b]]
    if (t < MM * Cc) {
        int b = t / Cc, c = t % Cc;
        out[(b0 + b) * Cc + c] = labels[bmu_i[b] * Cc + c];
    }

    // ---- per-class partials: gn = exp((d_bmu - d)/sig), fold rows, combine groups, fp16 write ----
    const float inv_sig = 1.f / sigma[0];
    __half* pb = ws_p + (long)blockIdx.x * NC;

    #pragma unroll
    for (int ti = 0; ti < 4; ++ti) {
        const int n0 = w * 64 + ti * 16;
        float sc[Cc];
        #pragma unroll
        for (int c = 0; c < Cc; ++c) sc[c] = 0.f;
        #pragma unroll
        for (int r = 0; r < 4; ++r) {
            int   row = g * 4 + r;
            float d2  = xs2s[row] + dvv[ti][r];
            float d   = sqrtf(d2 > 0.f ? d2 : 0.f);
            float gn  = expf((bmu_d[row] - d) * inv_sig);
            int   cl  = clss[row];
            #pragma unroll
            for (int c = 0; c < Cc; ++c) sc[c] += (cl == c) ? gn : 0.f;
        }
        #pragma unroll
        for (int c = 0; c < Cc; ++c) {
            float v = sc[c];
            v += __shfl_xor(v, 16);
            v += __shfl_xor(v, 32);
            if (g == 0) pb[c * Nn + n0 + c16] = __float2half(v);
        }
    }
}

// ---------------- final reduction: 160 j-blocks x 4 k-chunks (32 each) + histogram ----------------
__global__ __launch_bounds__(256) void som_fin(
    const float* __restrict__ act_in,
    const int*   __restrict__ cnt_in,
    const __half* __restrict__ ws_p,
    const int*   __restrict__ ws_cls,
    float* __restrict__ out)
{
    if (blockIdx.x < 160) {
        const int t  = threadIdx.x;
        const int kc = t & 3;                       // k-chunk 0..3 (32 partial-blocks each)
        const int j  = blockIdx.x * 64 + (t >> 2);  // j = c*Nn + n
        const int c  = j >> 10;
        const int n  = j & (Nn - 1);
        const __half* p = ws_p + (long)(kc * 32) * NC + j;
        float s = 0.f;
        #pragma unroll 8
        for (int i = 0; i < 32; ++i) s += __half2float(p[(long)i * NC]);
        s += __shfl_down(s, 2);
        s += __shfl_down(s, 1);
        if (kc == 0) out[ACT_OFF + n * Cc + c] = act_in[n * Cc + c] + s;
    } else {
        __shared__ int hist[Cc];
        if (threadIdx.x < Cc) hist[threadIdx.x] = 0;
        __syncthreads();
        for (int b = threadIdx.x; b < Bq; b += 256) atomicAdd(&hist[ws_cls[b]], 1);
        __syncthreads();
        if (threadIdx.x < Cc)
            out[CNT_OFF + threadIdx.x] = (float)(cnt_in[threadIdx.x] + hist[threadIdx.x]);
    }
}

// ---------------- fallback path (atomic-based, known-good) ----------------
__global__ void som_init(const float* __restrict__ act_in,
                         const int* __restrict__ cnt_in,
                         float* __restrict__ out) {
    int i = blockIdx.x * blockDim.x + threadIdx.x;
    if (i < Nn * Cc) out[ACT_OFF + i] = act_in[i];
    if (i < Cc) out[CNT_OFF + i] = (float)cnt_in[i];
}

__global__ __launch_bounds__(512) void som_main(
    const float* __restrict__ x,
    const float* __restrict__ y,
    const float* __restrict__ neurons,
    const float* __restrict__ labels,
    const float* __restrict__ sigma,
    float* __restrict__ out)
{
    __shared__ float xs[8][Dd];
    __shared__ float d2s[8][Nn];
    __shared__ float bmu_d[8];
    __shared__ int   bmu_i[8];
    __shared__ int   clss[8];

    const int t  = threadIdx.x;
    const int b0 = blockIdx.x * 8;

    for (int i = t; i < 8 * Dd; i += 512)
        xs[i >> 7][i & (Dd - 1)] = x[b0 * Dd + i];
    __syncthreads();

    float acc0[8], acc1[8];
    #pragma unroll
    for (int b = 0; b < 8; ++b) { acc0[b] = 0.f; acc1[b] = 0.f; }

    const float4* nr0 = (const float4*)(neurons + t * Dd);
    const float4* nr1 = (const float4*)(neurons + (t + 512) * Dd);

    #pragma unroll 2
    for (int dc = 0; dc < Dd / 4; ++dc) {
        float4 nv0 = nr0[dc];
        float4 nv1 = nr1[dc];
        #pragma unroll
        for (int b = 0; b < 8; ++b) {
            float4 xv = *(const float4*)&xs[b][dc * 4];
            float d;
            d = xv.x - nv0.x; acc0[b] = fmaf(d, d, acc0[b]);
            d = xv.y - nv0.y; acc0[b] = fmaf(d, d, acc0[b]);
            d = xv.z - nv0.z; acc0[b] = fmaf(d, d, acc0[b]);
            d = xv.w - nv0.w; acc0[b] = fmaf(d, d, acc0[b]);
            d = xv.x - nv1.x; acc1[b] = fmaf(d, d, acc1[b]);
            d = xv.y - nv1.y; acc1[b] = fmaf(d, d, acc1[b]);
            d = xv.z - nv1.z; acc1[b] = fmaf(d, d, acc1[b]);
            d = xv.w - nv1.w; acc1[b] = fmaf(d, d, acc1[b]);
        }
    }

    #pragma unroll
    for (int b = 0; b < 8; ++b) {
        d2s[b][t]       = acc0[b];
        d2s[b][t + 512] = acc1[b];
    }
    __syncthreads();

    {
        const int wv = t >> 6, lane = t & 63;
        float best = 3.4e38f; int bidx = 0;
        #pragma unroll
        for (int i = 0; i < Nn / 64; ++i) {
            int idx = lane + i * 64;
            float v = d2s[wv][idx];
            if (v < best) { best = v; bidx = idx; }
        }
        #pragma unroll
        for (int off = 32; off; off >>= 1) {
            float ov = __shfl_down(best, off);
            int   oi = __shfl_down(bidx, off);
            if (ov < best || (ov == best && oi < bidx)) { best = ov; bidx = oi; }
        }
        if (lane == 0) { bmu_i[wv] = bidx; bmu_d[wv] = sqrtf(best); }
    }

    if (t < 8) {
        const float* yr = y + (long)(b0 + t) * Cc;
        float bv = yr[0]; int bc = 0;
        #pragma unroll
        for (int c = 1; c < Cc; ++c) { float v = yr[c]; if (v > bv) { bv = v; bc = c; } }
        clss[t] = bc;
        atomicAdd(out + CNT_OFF + bc, 1.0f);
    }
    __syncthreads();

    for (int i = t; i < 8 * Cc; i += 512) {
        int b = i / Cc, c = i % Cc;
        out[(long)(b0 + b) * Cc + c] = labels[(long)bmu_i[b] * Cc + c];
    }

    const float sig = sigma[0];
    #pragma unroll
    for (int b = 0; b < 8; ++b) {
        float gb = expf(-bmu_d[b] / sig);
        int   cl = clss[b];
        float g0 = expf(-sqrtf(acc0[b]) / sig);
        float g1 = expf(-sqrtf(acc1[b]) / sig);
        float gn0 = (gb == 0.f) ? 0.f : g0 / gb;
        float gn1 = (gb == 0.f) ? 0.f : g1 / gb;
        atomicAdd(out + ACT_OFF + t * Cc + cl, gn0);
        atomicAdd(out + ACT_OFF + (t + 512) * Cc + cl, gn1);
    }
}

extern "C" void kernel_launch(void* const* d_in, const int* in_sizes, int n_in,
                              void* d_out, int out_size, void* d_ws, size_t ws_size,
                              hipStream_t stream) {
    const float* x       = (const float*)d_in[0];
    const float* y       = (const float*)d_in[1];
    const float* neurons = (const float*)d_in[2];
    const float* labels  = (const float*)d_in[3];
    const float* act     = (const float*)d_in[4];
    const int*   cnt     = (const int*)d_in[5];
    const float* sigma   = (const float*)d_in[6];
    float* out = (float*)d_out;

    if (ws_size >= (size_t)WS_NEED_BYTES) {
        char*   wsb    = (char*)d_ws;
        __half* ws_p   = (__half*)wsb;
        int*    ws_cls = (int*)(wsb + WS_CLS_BYTE);
        short8* ws_nbh = (short8*)(wsb + WS_NBH_BYTE);
        float*  ws_ns2 = (float*)(wsb + WS_NS2_BYTE);
        som_prep<<<128, 256, 0, stream>>>(neurons, ws_nbh, ws_ns2);
        som_dist<<<NBLK, NTH, 0, stream>>>(x, y, ws_nbh, ws_ns2, labels, sigma, out, ws_p, ws_cls);
        som_fin<<<161, 256, 0, stream>>>(act, cnt, ws_p, ws_cls, out);
    } else {
        som_init<<<(Nn * Cc + 255) / 256, 256, 0, stream>>>(act, cnt, out);
        som_main<<<Bq / 8, 512, 0, stream>>>(x, y, neurons, labels, sigma, out);
    }
}

// Round 19
// 30.068 us; speedup vs baseline: 1.4630x; 1.0592x over previous
//
#include <hip/hip_runtime.h>
#include <hip/hip_bf16.h>
#include <hip/hip_fp16.h>
#include <math.h>

#define Bq 2048
#define Nn 1024
#define Dd 128
#define Cc 10
#define MM 16                  // batch rows per block (MFMA M)
#define NBLK (Bq / MM)         // 128 dist-blocks
#define NTH 1024               // 16 waves
#define NC (Nn * Cc)           // 10240
#define PART_HALFS (NBLK * NC) // 1.31M halfs = 2.6 MB

// d_out layout (floats): [0, B*C) = labels[bmu]; [B*C, B*C+N*C) = activities; last C = counts
#define ACT_OFF (Bq * Cc)
#define CNT_OFF (Bq * Cc + Nn * Cc)

// ws layout (bytes): fp16 partials; cls ints; 256B-aligned nbh ([16][1024] x 16B); ns2
#define WS_CLS_BYTE  (PART_HALFS * 2)
#define WS_NBH_BYTE  (((WS_CLS_BYTE + Bq * 4) + 255) & ~255)
#define WS_NS2_BYTE  (WS_NBH_BYTE + 16 * Nn * 16)
#define WS_NEED_BYTES (WS_NS2_BYTE + Nn * 4)

typedef __attribute__((ext_vector_type(8))) short short8;   // 8 bf16 (4 VGPRs)
typedef __attribute__((ext_vector_type(4))) float f32x4;    // MFMA C/D

__device__ __forceinline__ ushort f2bf(float v, float* back) {
    __hip_bfloat16 h = __float2bfloat16(v);
    *back = __bfloat162float(h);
    return *(const ushort*)&h;
}

// ---------------- prep: neurons -> bf16 B-table nbh[kb][n] + ns2 of the ROUNDED values ----------------
// 128 blocks x 256 threads, 8 neuron rows per block. Metric becomes |x - bf16(n)|^2, computed
// consistently: dot uses bf16(n), ns2 = sum(bf16(n)^2) in fp32.
__global__ __launch_bounds__(256) void som_prep(
    const float* __restrict__ neurons,
    short8* __restrict__ nbh,   // [16][Nn]
    float* __restrict__ ns2)    // [Nn]
{
    __shared__ ushort hsh[8][128];
    const int t     = threadIdx.x;
    const int base8 = blockIdx.x * 8;    // 8 neuron rows per block

    // thread t: row r = t>>5, 4 consecutive elems at c = (t*4)&127
    const int r = t >> 5;
    const int c = (t * 4) & 127;
    float4 v = *(const float4*)&neurons[(long)(base8 + r) * Dd + c];
    float back, s;
    ushort h0 = f2bf(v.x, &back); s  = back * back;
    ushort h1 = f2bf(v.y, &back); s += back * back;
    ushort h2 = f2bf(v.z, &back); s += back * back;
    ushort h3 = f2bf(v.w, &back); s += back * back;
    hsh[r][c + 0] = h0;
    hsh[r][c + 1] = h1;
    hsh[r][c + 2] = h2;
    hsh[r][c + 3] = h3;

    // row-sum of back^2 over the 32 threads of this row (seg = t&31; xor stays in-row)
    #pragma unroll
    for (int off = 16; off; off >>= 1) s += __shfl_xor(s, off);
    if ((t & 31) == 0) ns2[base8 + r] = s;
    __syncthreads();

    // write 16B chunks: thread t<128 -> (r2 = t>>4, kb = t&15)
    if (t < 128) {
        int r2 = t >> 4, kb = t & 15;
        short8 H = *(const short8*)&hsh[r2][kb * 8];
        nbh[kb * Nn + base8 + r2] = H;
    }
}

// ---------------- main kernel: 2-pass split-x MFMA GEMM + fused argmin/partials ----------------
__global__ __launch_bounds__(NTH) void som_dist(
    const float* __restrict__ x,
    const float* __restrict__ y,
    const short8* __restrict__ nbh,   // [16][Nn]
    const float* __restrict__ ns2,
    const float* __restrict__ labels,
    const float* __restrict__ sigma,
    float* __restrict__ out,
    __half* __restrict__ ws_p,    // [NBLK][Cc][Nn] fp16
    int*   __restrict__ ws_cls)   // [Bq]
{
    __shared__ ushort xsh[MM * 128];   // swizzled bf16-hi of x rows (4 KB)
    __shared__ ushort xsl[MM * 128];   // bf16-lo (4 KB)
    __shared__ float  xs2s[MM];
    __shared__ float  candv[16][MM];
    __shared__ int    candi[16][MM];
    __shared__ float  bmu_d[MM];
    __shared__ int    bmu_i[MM];
    __shared__ int    clss[MM];

    const int t    = threadIdx.x;
    const int b0   = blockIdx.x * MM;
    const int w    = t >> 6;          // wave 0..15: owns cols w*64 .. +63
    const int lane = t & 63;
    const int g    = lane >> 4;       // 16-lane group 0..3
    const int c16  = lane & 15;

    // ---- stage x rows as split-bf16 in LDS (XOR-swizzled 16B chunks) ----
    #pragma unroll
    for (int ii = 0; ii < 2; ++ii) {
        int i   = t + ii * 1024;      // 0..2047
        int row = i >> 7;
        int k   = i & 127;
        float v = x[(b0 + row) * Dd + k];
        float back; ushort h = f2bf(v, &back);
        float lo = v - back;
        float b2; ushort l = f2bf(lo, &b2);
        int kb  = k >> 3, j = k & 7;
        int idx = row * 128 + ((kb ^ (row & 7)) << 3) + j;
        xsh[idx] = h;
        xsl[idx] = l;
    }

    // xs2[row w] (exact fp32)
    {
        float v0 = x[(b0 + w) * Dd + lane];
        float v1 = x[(b0 + w) * Dd + lane + 64];
        float s  = fmaf(v0, v0, v1 * v1);
        #pragma unroll
        for (int off = 32; off; off >>= 1) s += __shfl_xor(s, off);
        if (lane == 0) xs2s[w] = s;
    }
    __syncthreads();

    // ---- MFMA: dot[b][n] = (xh + xl) . nb  (2-pass split-x, fp32 accum) ----
    float dvv[4][4];                  // shifted distance per (tile, reg)
    float mval[4]; int midx[4];
    #pragma unroll
    for (int r = 0; r < 4; ++r) { mval[r] = 3.4e38f; midx[r] = 0; }

    const int rowa   = c16;           // A-frag row for this lane
    const int abase  = rowa * 128;
    const int axor   = (rowa & 7);

    #pragma unroll
    for (int ti = 0; ti < 4; ++ti) {
        const int n0 = w * 64 + ti * 16;
        f32x4 acc = {0.f, 0.f, 0.f, 0.f};
        #pragma unroll
        for (int ks = 0; ks < 4; ++ks) {
            const int kb = ks * 4 + g;                       // 16B k-chunk index
            const int ai = abase + ((kb ^ axor) << 3);
            short8 ah = *(const short8*)&xsh[ai];
            short8 al = *(const short8*)&xsl[ai];
            short8 bh = nbh[kb * Nn + n0 + c16];
            acc = __builtin_amdgcn_mfma_f32_16x16x32_bf16(ah, bh, acc, 0, 0, 0);
            acc = __builtin_amdgcn_mfma_f32_16x16x32_bf16(al, bh, acc, 0, 0, 0);
        }
        const float ns2v = ns2[n0 + c16];
        #pragma unroll
        for (int r = 0; r < 4; ++r) {
            float dv = fmaf(-2.f, acc[r], ns2v);   // shifted d2 (argmin-safe)
            dvv[ti][r] = dv;
            if (dv < mval[r]) { mval[r] = dv; midx[r] = n0 + c16; }  // n ascending with ti: strict < keeps first
        }
    }

    // ---- argmin: reduce the 16 lanes of each group (row = g*4+r), then 16-wave combine ----
    #pragma unroll
    for (int r = 0; r < 4; ++r) {
        float bv = mval[r]; int bi = midx[r];
        #pragma unroll
        for (int off = 8; off; off >>= 1) {
            float ov = __shfl_xor(bv, off);
            int   oi = __shfl_xor(bi, off);
            if (ov < bv || (ov == bv && oi < bi)) { bv = ov; bi = oi; }
        }
        if (c16 == 0) { candv[w][g * 4 + r] = bv; candi[w][g * 4 + r] = bi; }
    }
    __syncthreads();

    if (t < MM) {
        float best = candv[0][t]; int bidx = candi[0][t];
        #pragma unroll
        for (int w2 = 1; w2 < 16; ++w2) {
            float v = candv[w2][t]; int i2 = candi[w2][t];
            if (v < best || (v == best && i2 < bidx)) { best = v; bidx = i2; }
        }
        bmu_i[t] = bidx;
        float d2 = xs2s[t] + best;
        bmu_d[t] = sqrtf(d2 > 0.f ? d2 : 0.f);

        // cls = argmax_c y[b][c] (strict > keeps first)
        const float* yr = y + (long)(b0 + t) * Cc;
        float bvv = yr[0]; int bc = 0;
        #pragma unroll
        for (int c = 1; c < Cc; ++c) { float v = yr[c]; if (v > bvv) { bvv = v; bc = c; } }
        clss[t] = bc;
        ws_cls[b0 + t] = bc;
    }
    __syncthreads();

    // out rows: labels[bmu[b]]
    if (t < MM * Cc) {
        int b = t / Cc, c = t % Cc;
        out[(b0 + b) * Cc + c] = labels[bmu_i[b] * Cc + c];
    }

    // ---- per-class partials: gn = exp((d_bmu - d)/sig), fold rows, combine groups, fp16 write ----
    const float inv_sig = 1.f / sigma[0];
    __half* pb = ws_p + (long)blockIdx.x * NC;

    #pragma unroll
    for (int ti = 0; ti < 4; ++ti) {
        const int n0 = w * 64 + ti * 16;
        float sc[Cc];
        #pragma unroll
        for (int c = 0; c < Cc; ++c) sc[c] = 0.f;
        #pragma unroll
        for (int r = 0; r < 4; ++r) {
            int   row = g * 4 + r;
            float d2  = xs2s[row] + dvv[ti][r];
            float d   = sqrtf(d2 > 0.f ? d2 : 0.f);
            float gn  = expf((bmu_d[row] - d) * inv_sig);
            int   cl  = clss[row];
            #pragma unroll
            for (int c = 0; c < Cc; ++c) sc[c] += (cl == c) ? gn : 0.f;
        }
        #pragma unroll
        for (int c = 0; c < Cc; ++c) {
            float v = sc[c];
            v += __shfl_xor(v, 16);
            v += __shfl_xor(v, 32);
            if (g == 0) pb[c * Nn + n0 + c16] = __float2half(v);
        }
    }
}

// ---------------- final reduction: 160 j-blocks x 4 k-chunks (32 each) + histogram ----------------
__global__ __launch_bounds__(256) void som_fin(
    const float* __restrict__ act_in,
    const int*   __restrict__ cnt_in,
    const __half* __restrict__ ws_p,
    const int*   __restrict__ ws_cls,
    float* __restrict__ out)
{
    if (blockIdx.x < 160) {
        const int t  = threadIdx.x;
        const int kc = t & 3;                       // k-chunk 0..3 (32 partial-blocks each)
        const int j  = blockIdx.x * 64 + (t >> 2);  // j = c*Nn + n
        const int c  = j >> 10;
        const int n  = j & (Nn - 1);
        const __half* p = ws_p + (long)(kc * 32) * NC + j;
        float s = 0.f;
        #pragma unroll 8
        for (int i = 0; i < 32; ++i) s += __half2float(p[(long)i * NC]);
        s += __shfl_down(s, 2);
        s += __shfl_down(s, 1);
        if (kc == 0) out[ACT_OFF + n * Cc + c] = act_in[n * Cc + c] + s;
    } else {
        __shared__ int hist[Cc];
        if (threadIdx.x < Cc) hist[threadIdx.x] = 0;
        __syncthreads();
        for (int b = threadIdx.x; b < Bq; b += 256) atomicAdd(&hist[ws_cls[b]], 1);
        __syncthreads();
        if (threadIdx.x < Cc)
            out[CNT_OFF + threadIdx.x] = (float)(cnt_in[threadIdx.x] + hist[threadIdx.x]);
    }
}

// ---------------- fallback path (atomic-based, known-good) ----------------
__global__ void som_init(const float* __restrict__ act_in,
                         const int* __restrict__ cnt_in,
                         float* __restrict__ out) {
    int i = blockIdx.x * blockDim.x + threadIdx.x;
    if (i < Nn * Cc) out[ACT_OFF + i] = act_in[i];
    if (i < Cc) out[CNT_OFF + i] = (float)cnt_in[i];
}

__global__ __launch_bounds__(512) void som_main(
    const float* __restrict__ x,
    const float* __restrict__ y,
    const float* __restrict__ neurons,
    const float* __restrict__ labels,
    const float* __restrict__ sigma,
    float* __restrict__ out)
{
    __shared__ float xs[8][Dd];
    __shared__ float d2s[8][Nn];
    __shared__ float bmu_d[8];
    __shared__ int   bmu_i[8];
    __shared__ int   clss[8];

    const int t  = threadIdx.x;
    const int b0 = blockIdx.x * 8;

    for (int i = t; i < 8 * Dd; i += 512)
        xs[i >> 7][i & (Dd - 1)] = x[b0 * Dd + i];
    __syncthreads();

    float acc0[8], acc1[8];
    #pragma unroll
    for (int b = 0; b < 8; ++b) { acc0[b] = 0.f; acc1[b] = 0.f; }

    const float4* nr0 = (const float4*)(neurons + t * Dd);
    const float4* nr1 = (const float4*)(neurons + (t + 512) * Dd);

    #pragma unroll 2
    for (int dc = 0; dc < Dd / 4; ++dc) {
        float4 nv0 = nr0[dc];
        float4 nv1 = nr1[dc];
        #pragma unroll
        for (int b = 0; b < 8; ++b) {
            float4 xv = *(const float4*)&xs[b][dc * 4];
            float d;
            d = xv.x - nv0.x; acc0[b] = fmaf(d, d, acc0[b]);
            d = xv.y - nv0.y; acc0[b] = fmaf(d, d, acc0[b]);
            d = xv.z - nv0.z; acc0[b] = fmaf(d, d, acc0[b]);
            d = xv.w - nv0.w; acc0[b] = fmaf(d, d, acc0[b]);
            d = xv.x - nv1.x; acc1[b] = fmaf(d, d, acc1[b]);
            d = xv.y - nv1.y; acc1[b] = fmaf(d, d, acc1[b]);
            d = xv.z - nv1.z; acc1[b] = fmaf(d, d, acc1[b]);
            d = xv.w - nv1.w; acc1[b] = fmaf(d, d, acc1[b]);
        }
    }

    #pragma unroll
    for (int b = 0; b < 8; ++b) {
        d2s[b][t]       = acc0[b];
        d2s[b][t + 512] = acc1[b];
    }
    __syncthreads();

    {
        const int wv = t >> 6, lane = t & 63;
        float best = 3.4e38f; int bidx = 0;
        #pragma unroll
        for (int i = 0; i < Nn / 64; ++i) {
            int idx = lane + i * 64;
            float v = d2s[wv][idx];
            if (v < best) { best = v; bidx = idx; }
        }
        #pragma unroll
        for (int off = 32; off; off >>= 1) {
            float ov = __shfl_down(best, off);
            int   oi = __shfl_down(bidx, off);
            if (ov < best || (ov == best && oi < bidx)) { best = ov; bidx = oi; }
        }
        if (lane == 0) { bmu_i[wv] = bidx; bmu_d[wv] = sqrtf(best); }
    }

    if (t < 8) {
        const float* yr = y + (long)(b0 + t) * Cc;
        float bv = yr[0]; int bc = 0;
        #pragma unroll
        for (int c = 1; c < Cc; ++c) { float v = yr[c]; if (v > bv) { bv = v; bc = c; } }
        clss[t] = bc;
        atomicAdd(out + CNT_OFF + bc, 1.0f);
    }
    __syncthreads();

    for (int i = t; i < 8 * Cc; i += 512) {
        int b = i / Cc, c = i % Cc;
        out[(long)(b0 + b) * Cc + c] = labels[(long)bmu_i[b] * Cc + c];
    }

    const float sig = sigma[0];
    #pragma unroll
    for (int b = 0; b < 8; ++b) {
        float gb = expf(-bmu_d[b] / sig);
        int   cl = clss[b];
        float g0 = expf(-sqrtf(acc0[b]) / sig);
        float g1 = expf(-sqrtf(acc1[b]) / sig);
        float gn0 = (gb == 0.f) ? 0.f : g0 / gb;
        float gn1 = (gb == 0.f) ? 0.f : g1 / gb;
        atomicAdd(out + ACT_OFF + t * Cc + cl, gn0);
        atomicAdd(out + ACT_OFF + (t + 512) * Cc + cl, gn1);
    }
}

extern "C" void kernel_launch(void* const* d_in, const int* in_sizes, int n_in,
                              void* d_out, int out_size, void* d_ws, size_t ws_size,
                              hipStream_t stream) {
    const float* x       = (const float*)d_in[0];
    const float* y       = (const float*)d_in[1];
    const float* neurons = (const float*)d_in[2];
    const float* labels  = (const float*)d_in[3];
    const float* act     = (const float*)d_in[4];
    const int*   cnt     = (const int*)d_in[5];
    const float* sigma   = (const float*)d_in[6];
    float* out = (float*)d_out;

    if (ws_size >= (size_t)WS_NEED_BYTES) {
        char*   wsb    = (char*)d_ws;
        __half* ws_p   = (__half*)wsb;
        int*    ws_cls = (int*)(wsb + WS_CLS_BYTE);
        short8* ws_nbh = (short8*)(wsb + WS_NBH_BYTE);
        float*  ws_ns2 = (float*)(wsb + WS_NS2_BYTE);
        som_prep<<<128, 256, 0, stream>>>(neurons, ws_nbh, ws_ns2);
        som_dist<<<NBLK, NTH, 0, stream>>>(x, y, ws_nbh, ws_ns2, labels, sigma, out, ws_p, ws_cls);
        som_fin<<<161, 256, 0, stream>>>(act, cnt, ws_p, ws_cls, out);
    } else {
        som_init<<<(Nn * Cc + 255) / 256, 256, 0, stream>>>(act, cnt, out);
        som_main<<<Bq / 8, 512, 0, stream>>>(x, y, neurons, labels, sigma, out);
    }
}